// Round 1
// baseline (408.389 us; speedup 1.0000x reference)
//
#include <hip/hip_runtime.h>
#include <hip/hip_bf16.h>
#include <stdint.h>

// GraphNet global block, MI355X. Phase1: fused 3-layer node MLP (f16 MFMA,
// fp32 acc) + LN + atomic segment-sum. Phase2: per-graph MLP in fp32 (tiny).
// agg buffer aliases d_out (4096*64 fp32 = 1 MB, read before overwrite).

#define NNODES 500000
#define NGRAPHS 4096
#define ROWS 128      // node rows per block
#define LDH 136       // padded f16 row stride (272 B: 16B-aligned, conflict-free)

typedef __attribute__((ext_vector_type(8))) _Float16 half8;
typedef __attribute__((ext_vector_type(4))) float floatx4;

// ---------------- prep: transpose weights to f16 [N][K] in ws ----------------
__global__ void prep_kernel(const float* __restrict__ w1, const float* __restrict__ w2,
                            const float* __restrict__ w3,
                            _Float16* __restrict__ w1T, _Float16* __restrict__ w2T,
                            _Float16* __restrict__ w3T) {
    int i = blockIdx.x * 256 + threadIdx.x;   // 0..16383
    if (i < 128 * 128) {
        int n = i >> 7, k = i & 127;
        w1T[i] = (_Float16)w1[k * 128 + n];
        w2T[i] = (_Float16)w2[k * 128 + n];
    }
    if (i < 64 * 128) {
        int n = i >> 7, k = i & 127;
        w3T[i] = (_Float16)w3[k * 64 + n];
    }
}

// ---------------- phase 1: per-node MLP + LN + atomic scatter ----------------
__global__ __launch_bounds__(256, 2) void node_kernel(
    const float* __restrict__ x, const float* __restrict__ u, const int* __restrict__ batch,
    const _Float16* __restrict__ w1T, const _Float16* __restrict__ w2T,
    const _Float16* __restrict__ w3T,
    const float* __restrict__ b1, const float* __restrict__ b2, const float* __restrict__ b3,
    const float* __restrict__ lng, const float* __restrict__ lnb,
    float* __restrict__ agg)
{
    __shared__ __align__(16) _Float16 hA[ROWS * LDH];
    __shared__ int sBatch[ROWS];

    const int tid = threadIdx.x;
    const int rowbase = blockIdx.x * ROWS;
    const int wave = tid >> 6;
    const int lane = tid & 63;
    const int q = lane >> 4;      // quad (k-block / row-block selector)
    const int l16 = lane & 15;

    // stage batch indices
    for (int r = tid; r < ROWS; r += 256) {
        int gr = rowbase + r;
        sBatch[r] = (gr < NNODES) ? batch[gr] : 0;
    }
    __syncthreads();

    // stage h0 = concat(x, u[batch]) as f16
    for (int i = tid; i < ROWS * 16; i += 256) {
        int r = i >> 4, c4 = (i & 15) << 2;
        int gr = rowbase + r;
        float4 vx = make_float4(0.f, 0.f, 0.f, 0.f);
        if (gr < NNODES) vx = *(const float4*)(x + (size_t)gr * 64 + c4);
        _Float16* p = &hA[r * LDH + c4];
        p[0] = (_Float16)vx.x; p[1] = (_Float16)vx.y;
        p[2] = (_Float16)vx.z; p[3] = (_Float16)vx.w;
        int g = sBatch[r];
        float4 vu = *(const float4*)(u + (size_t)g * 64 + c4);
        _Float16* p2 = &hA[r * LDH + 64 + c4];
        p2[0] = (_Float16)vu.x; p2[1] = (_Float16)vu.y;
        p2[2] = (_Float16)vu.z; p2[3] = (_Float16)vu.w;
    }
    __syncthreads();

    // ---- layers 1 & 2: 128x128, relu, in-place in hA ----
    const int rowg = (wave >> 1) * 64;
    const int colg = (wave & 1) * 64;
    for (int layer = 0; layer < 2; ++layer) {
        const _Float16* wT = layer ? w2T : w1T;
        const float* bias = layer ? b2 : b1;
        floatx4 acc[4][4];
        #pragma unroll
        for (int ct = 0; ct < 4; ++ct) {
            float bv = bias[colg + ct * 16 + l16];
            #pragma unroll
            for (int rt = 0; rt < 4; ++rt) acc[rt][ct] = (floatx4){bv, bv, bv, bv};
        }
        half8 bfr[4][4];
        #pragma unroll
        for (int ks = 0; ks < 4; ++ks)
            #pragma unroll
            for (int ct = 0; ct < 4; ++ct)
                bfr[ks][ct] = *(const half8*)(wT + (colg + ct * 16 + l16) * 128 + ks * 32 + q * 8);
        #pragma unroll
        for (int ks = 0; ks < 4; ++ks) {
            half8 af[4];
            #pragma unroll
            for (int rt = 0; rt < 4; ++rt)
                af[rt] = *(const half8*)(&hA[(rowg + rt * 16 + l16) * LDH + ks * 32 + q * 8]);
            #pragma unroll
            for (int rt = 0; rt < 4; ++rt)
                #pragma unroll
                for (int ct = 0; ct < 4; ++ct)
                    acc[rt][ct] = __builtin_amdgcn_mfma_f32_16x16x32_f16(
                        af[rt], bfr[ks][ct], acc[rt][ct], 0, 0, 0);
        }
        __syncthreads();   // all reads of hA complete
        #pragma unroll
        for (int rt = 0; rt < 4; ++rt)
            #pragma unroll
            for (int ct = 0; ct < 4; ++ct)
                #pragma unroll
                for (int j = 0; j < 4; ++j) {
                    float v = acc[rt][ct][j];
                    v = v > 0.f ? v : 0.f;
                    hA[(rowg + rt * 16 + q * 4 + j) * LDH + colg + ct * 16 + l16] = (_Float16)v;
                }
        __syncthreads();   // writes visible
    }

    // ---- layer 3: 128x64 + LN + atomic scatter ----
    {
        const int rowg3 = wave * 32;   // 4 waves x 32 rows
        floatx4 acc[2][4];
        #pragma unroll
        for (int ct = 0; ct < 4; ++ct) {
            float bv = b3[ct * 16 + l16];
            acc[0][ct] = (floatx4){bv, bv, bv, bv};
            acc[1][ct] = (floatx4){bv, bv, bv, bv};
        }
        half8 bfr[4][4];
        #pragma unroll
        for (int ks = 0; ks < 4; ++ks)
            #pragma unroll
            for (int ct = 0; ct < 4; ++ct)
                bfr[ks][ct] = *(const half8*)(w3T + (ct * 16 + l16) * 128 + ks * 32 + q * 8);
        #pragma unroll
        for (int ks = 0; ks < 4; ++ks) {
            half8 af[2];
            #pragma unroll
            for (int rt = 0; rt < 2; ++rt)
                af[rt] = *(const half8*)(&hA[(rowg3 + rt * 16 + l16) * LDH + ks * 32 + q * 8]);
            #pragma unroll
            for (int rt = 0; rt < 2; ++rt)
                #pragma unroll
                for (int ct = 0; ct < 4; ++ct)
                    acc[rt][ct] = __builtin_amdgcn_mfma_f32_16x16x32_f16(
                        af[rt], bfr[ks][ct], acc[rt][ct], 0, 0, 0);
        }
        float gct[4], bct[4];
        #pragma unroll
        for (int ct = 0; ct < 4; ++ct) {
            gct[ct] = lng[ct * 16 + l16];
            bct[ct] = lnb[ct * 16 + l16];
        }
        #pragma unroll
        for (int rt = 0; rt < 2; ++rt)
            #pragma unroll
            for (int j = 0; j < 4; ++j) {
                int rloc = rowg3 + rt * 16 + q * 4 + j;   // quad-uniform row
                float v0 = acc[rt][0][j], v1 = acc[rt][1][j];
                float v2 = acc[rt][2][j], v3 = acc[rt][3][j];
                float s = v0 + v1 + v2 + v3;
                float ss = v0 * v0 + v1 * v1 + v2 * v2 + v3 * v3;
                #pragma unroll
                for (int m = 1; m < 16; m <<= 1) {
                    s += __shfl_xor(s, m, 16);
                    ss += __shfl_xor(ss, m, 16);
                }
                float mean = s * (1.f / 64.f);
                float var = ss * (1.f / 64.f) - mean * mean;
                float rstd = rsqrtf(var + 1e-5f);
                if (rowbase + rloc < NNODES) {
                    float* dst = agg + (size_t)sBatch[rloc] * 64;
                    unsafeAtomicAdd(dst + 0 + l16,  (v0 - mean) * rstd * gct[0] + bct[0]);
                    unsafeAtomicAdd(dst + 16 + l16, (v1 - mean) * rstd * gct[1] + bct[1]);
                    unsafeAtomicAdd(dst + 32 + l16, (v2 - mean) * rstd * gct[2] + bct[2]);
                    unsafeAtomicAdd(dst + 48 + l16, (v3 - mean) * rstd * gct[3] + bct[3]);
                }
            }
    }
}

// ---------------- phase 2: per-graph MLP (fp32, one wave per graph) ----------
__global__ __launch_bounds__(256, 4) void graph_kernel(
    const float* __restrict__ u,
    const float* __restrict__ w4, const float* __restrict__ b4,
    const float* __restrict__ w5, const float* __restrict__ b5,
    const float* __restrict__ w6, const float* __restrict__ b6,
    const float* __restrict__ g2, const float* __restrict__ bb2,
    float* __restrict__ out)   // out also holds agg on entry
{
    __shared__ float z[4][2][128];
    const int wave = threadIdx.x >> 6, lane = threadIdx.x & 63;
    const int g = blockIdx.x * 4 + wave;
    float* za = z[wave][0];
    float* zb = z[wave][1];
    za[lane] = out[(size_t)g * 64 + lane];        // agg row (read before overwrite)
    za[64 + lane] = u[(size_t)g * 64 + lane];
    float s0 = b4[lane], s1 = b4[64 + lane];
    for (int k = 0; k < 128; ++k) {
        float zk = za[k];
        s0 = fmaf(zk, w4[k * 128 + lane], s0);
        s1 = fmaf(zk, w4[k * 128 + 64 + lane], s1);
    }
    zb[lane] = fmaxf(s0, 0.f); zb[64 + lane] = fmaxf(s1, 0.f);
    s0 = b5[lane]; s1 = b5[64 + lane];
    for (int k = 0; k < 128; ++k) {
        float zk = zb[k];
        s0 = fmaf(zk, w5[k * 128 + lane], s0);
        s1 = fmaf(zk, w5[k * 128 + 64 + lane], s1);
    }
    za[lane] = fmaxf(s0, 0.f); za[64 + lane] = fmaxf(s1, 0.f);
    float s = b6[lane];
    for (int k = 0; k < 128; ++k) s = fmaf(za[k], w6[k * 64 + lane], s);
    float sum = s, ssq = s * s;
    #pragma unroll
    for (int m = 1; m < 64; m <<= 1) {
        sum += __shfl_xor(sum, m, 64);
        ssq += __shfl_xor(ssq, m, 64);
    }
    float mean = sum * (1.f / 64.f);
    float var = ssq * (1.f / 64.f) - mean * mean;
    float rstd = rsqrtf(var + 1e-5f);
    out[(size_t)g * 64 + lane] =
        (s - mean) * rstd * g2[lane] + bb2[lane] + u[(size_t)g * 64 + lane];
}

extern "C" void kernel_launch(void* const* d_in, const int* in_sizes, int n_in,
                              void* d_out, int out_size, void* d_ws, size_t ws_size,
                              hipStream_t stream) {
    const float* x   = (const float*)d_in[0];
    const float* u   = (const float*)d_in[1];
    const int*   bt  = (const int*)d_in[2];
    const float* w1  = (const float*)d_in[3];
    const float* b1  = (const float*)d_in[4];
    const float* w2  = (const float*)d_in[5];
    const float* b2  = (const float*)d_in[6];
    const float* w3  = (const float*)d_in[7];
    const float* b3  = (const float*)d_in[8];
    const float* lng = (const float*)d_in[9];
    const float* lnb = (const float*)d_in[10];
    const float* w4  = (const float*)d_in[11];
    const float* b4  = (const float*)d_in[12];
    const float* w5  = (const float*)d_in[13];
    const float* b5  = (const float*)d_in[14];
    const float* w6  = (const float*)d_in[15];
    const float* b6  = (const float*)d_in[16];
    const float* g2  = (const float*)d_in[17];
    const float* bb2 = (const float*)d_in[18];
    float* out = (float*)d_out;

    _Float16* w1T = (_Float16*)d_ws;
    _Float16* w2T = w1T + 128 * 128;
    _Float16* w3T = w2T + 128 * 128;

    hipMemsetAsync(d_out, 0, (size_t)NGRAPHS * 64 * sizeof(float), stream);
    prep_kernel<<<64, 256, 0, stream>>>(w1, w2, w3, w1T, w2T, w3T);
    node_kernel<<<(NNODES + ROWS - 1) / ROWS, 256, 0, stream>>>(
        x, u, bt, w1T, w2T, w3T, b1, b2, b3, lng, lnb, out);
    graph_kernel<<<NGRAPHS / 4, 256, 0, stream>>>(
        u, w4, b4, w5, b5, w6, b6, g2, bb2, out);
}